// Round 1
// baseline (151.595 us; speedup 1.0000x reference)
//
#include <hip/hip_runtime.h>

#define IDIM   78464
#define XCOLS  78466   // IDIM + 2 (female, age)
#define PCD    1936
#define PCD2   1938
#define KK     9
#define CC     600
#define BB     256

// ws layout (float offsets):
//  [0    .. 1937]  v   (scatter of w2[k]*w1[k,c] by feats)
//  [2048 .. 2304]  rowsums (256 x-row dots + 1 slot for c.u)
//  [4096 .. 4096+IDIM-1]  u = R @ v
#define WS_V    0
#define WS_SUMS 2048
#define WS_U    4096

__global__ void k0_zero(float* ws) {
    int i = blockIdx.x * blockDim.x + threadIdx.x;
    if (i < PCD2) ws[WS_V + i] = 0.0f;
}

__global__ void k1_scatter(const int* __restrict__ feats, const float* __restrict__ w1,
                           const float* __restrict__ w2, float* ws) {
    int t = blockIdx.x * blockDim.x + threadIdx.x;
    if (t < KK * CC) {
        int k = t / CC;
        atomicAdd(&ws[WS_V + feats[t]], w2[k] * w1[t]);
    }
}

// u[row] = dot(rot[row, :], v)   — wave per row, float4 coalesced loads
__global__ __launch_bounds__(256) void k2_matvec(const float* __restrict__ rot,
                                                 const float* __restrict__ v_in,
                                                 float* __restrict__ u) {
    __shared__ __align__(16) float vlds[PCD];
    for (int i = threadIdx.x; i < PCD; i += 256) vlds[i] = v_in[i];
    __syncthreads();

    const int wave = threadIdx.x >> 6;
    const int lane = threadIdx.x & 63;
    const int nw   = gridDim.x << 2;           // total waves
    const float4* v4 = reinterpret_cast<const float4*>(vlds);

    for (int row = (blockIdx.x << 2) + wave; row < IDIM; row += nw) {
        const float4* r4 = reinterpret_cast<const float4*>(rot + (size_t)row * PCD);
        float ax = 0.f, ay = 0.f, az = 0.f, aw = 0.f;
        #pragma unroll
        for (int it = 0; it < 7; ++it) {        // 7 full iterations: j in [0, 448)
            int j = lane + (it << 6);
            float4 a = r4[j];
            float4 b = v4[j];
            ax += a.x * b.x; ay += a.y * b.y; az += a.z * b.z; aw += a.w * b.w;
        }
        {                                        // tail: 484 float4 per row total
            int j = lane + 448;
            if (j < PCD / 4) {
                float4 a = r4[j];
                float4 b = v4[j];
                ax += a.x * b.x; ay += a.y * b.y; az += a.z * b.z; aw += a.w * b.w;
            }
        }
        float s = (ax + ay) + (az + aw);
        #pragma unroll
        for (int off = 32; off; off >>= 1) s += __shfl_down(s, off, 64);
        if (lane == 0) u[row] = s;
    }
}

// rowsums[b] = dot(x[b, :IDIM], u) for b<256;  rowsums[256] = dot(center, u)
// float2 loads: odd rows of x are only 8B-aligned (row stride 78466 floats)
__global__ __launch_bounds__(1024) void k3_rowdot(const float* __restrict__ x,
                                                  const float* __restrict__ center,
                                                  const float* __restrict__ u,
                                                  float* __restrict__ sums) {
    __shared__ float wred[16];
    const int b = blockIdx.x;
    const float* row = (b < BB) ? (x + (size_t)b * XCOLS) : center;
    const float2* r2 = reinterpret_cast<const float2*>(row);
    const float2* u2 = reinterpret_cast<const float2*>(u);
    float ax = 0.f, ay = 0.f;
    for (int j = threadIdx.x; j < IDIM / 2; j += 1024) {
        float2 a = r2[j];
        float2 c = u2[j];
        ax += a.x * c.x; ay += a.y * c.y;
    }
    float s = ax + ay;
    #pragma unroll
    for (int off = 32; off; off >>= 1) s += __shfl_down(s, off, 64);
    const int wave = threadIdx.x >> 6;
    const int lane = threadIdx.x & 63;
    if (lane == 0) wred[wave] = s;
    __syncthreads();
    if (threadIdx.x == 0) {
        float t = 0.f;
        #pragma unroll
        for (int w = 0; w < 16; ++w) t += wred[w];
        sums[b] = t;
    }
}

// out[b] = rowsums[b] - c.u + female*(v[1936]+w2[10]) + age*(v[1937]+w2[9]) + sum_k b1[k]*w2[k] + b2
__global__ void k4_final(const float* __restrict__ x, const float* __restrict__ b1,
                         const float* __restrict__ w2, const float* __restrict__ b2,
                         const float* __restrict__ ws, float* __restrict__ out) {
    int b = threadIdx.x;
    if (b < BB) {
        float female = x[(size_t)b * XCOLS + IDIM];
        float age    = x[(size_t)b * XCOLS + IDIM + 1];
        float cu     = ws[WS_SUMS + 256];
        float cst = b2[0];
        #pragma unroll
        for (int k = 0; k < KK; ++k) cst += b1[k] * w2[k];
        float r = ws[WS_SUMS + b] - cu
                + female * (ws[WS_V + 1936] + w2[10])
                + age    * (ws[WS_V + 1937] + w2[9])
                + cst;
        out[b] = r;
    }
}

extern "C" void kernel_launch(void* const* d_in, const int* in_sizes, int n_in,
                              void* d_out, int out_size, void* d_ws, size_t ws_size,
                              hipStream_t stream) {
    const float* x      = (const float*)d_in[0];
    const float* center = (const float*)d_in[1];
    const float* rot    = (const float*)d_in[2];
    const int*   feats  = (const int*)  d_in[3];
    const float* w1     = (const float*)d_in[4];
    const float* b1     = (const float*)d_in[5];
    const float* w2     = (const float*)d_in[6];
    const float* b2     = (const float*)d_in[7];
    float* ws  = (float*)d_ws;
    float* out = (float*)d_out;

    hipLaunchKernelGGL(k0_zero,    dim3(8),    dim3(256),  0, stream, ws);
    hipLaunchKernelGGL(k1_scatter, dim3(22),   dim3(256),  0, stream, feats, w1, w2, ws);
    hipLaunchKernelGGL(k2_matvec,  dim3(2048), dim3(256),  0, stream, rot, ws + WS_V, ws + WS_U);
    hipLaunchKernelGGL(k3_rowdot,  dim3(257),  dim3(1024), 0, stream, x, center, ws + WS_U, ws + WS_SUMS);
    hipLaunchKernelGGL(k4_final,   dim3(1),    dim3(256),  0, stream, x, b1, w2, b2, ws, out);
}

// Round 2
// 136.998 us; speedup vs baseline: 1.1065x; 1.1065x over previous
//
#include <hip/hip_runtime.h>

#define IDIM   78464
#define XCOLS  78466   // IDIM + 2 (female, age)
#define PCD    1936
#define PCD2   1938
#define KK     9
#define CC     600
#define BB     256
#define CH     8       // chunks per row-dot in k3
#define CHLEN  (IDIM / CH / 2)   // float2 elements per chunk = 4904

typedef float f4 __attribute__((ext_vector_type(4)));
typedef float f2 __attribute__((ext_vector_type(2)));

// ws layout (float offsets):
//  [0    .. 1937]                 v   (scatter of w2[k]*w1[k,c] by feats)
//  [2048 .. 2048+257*8-1]         partial row-dots [257][8] (row 256 = center)
//  [8192 .. 8192+IDIM-1]          u = R @ v
#define WS_V    0
#define WS_P    2048
#define WS_U    8192

// build v in LDS (zero + scatter via LDS atomics), write out. One block.
__global__ __launch_bounds__(1024) void k1_buildv(const int* __restrict__ feats,
                                                  const float* __restrict__ w1,
                                                  const float* __restrict__ w2,
                                                  float* __restrict__ v) {
    __shared__ float vl[PCD2];
    for (int i = threadIdx.x; i < PCD2; i += 1024) vl[i] = 0.0f;
    __syncthreads();
    for (int t = threadIdx.x; t < KK * CC; t += 1024) {
        int k = t / CC;
        atomicAdd(&vl[feats[t]], w2[k] * w1[t]);
    }
    __syncthreads();
    for (int i = threadIdx.x; i < PCD2; i += 1024) v[i] = vl[i];
}

// u[row] = dot(rot[row, :], v)   — wave per row, float4 nontemporal loads
__global__ __launch_bounds__(256) void k2_matvec(const float* __restrict__ rot,
                                                 const float* __restrict__ v_in,
                                                 float* __restrict__ u) {
    __shared__ __align__(16) float vlds[PCD];
    for (int i = threadIdx.x; i < PCD; i += 256) vlds[i] = v_in[i];
    __syncthreads();

    const int wave = threadIdx.x >> 6;
    const int lane = threadIdx.x & 63;
    const int nw   = gridDim.x << 2;           // total waves
    const f4* v4 = reinterpret_cast<const f4*>(vlds);

    for (int row = (blockIdx.x << 2) + wave; row < IDIM; row += nw) {
        const f4* r4 = reinterpret_cast<const f4*>(rot + (size_t)row * PCD);
        float ax = 0.f, ay = 0.f, az = 0.f, aw = 0.f;
        #pragma unroll
        for (int it = 0; it < 7; ++it) {        // j in [0, 448)
            int j = lane + (it << 6);
            f4 a = __builtin_nontemporal_load(&r4[j]);
            f4 b = v4[j];
            ax += a.x * b.x; ay += a.y * b.y; az += a.z * b.z; aw += a.w * b.w;
        }
        {                                        // tail: 484 float4 per row total
            int j = lane + 448;
            if (j < PCD / 4) {
                f4 a = __builtin_nontemporal_load(&r4[j]);
                f4 b = v4[j];
                ax += a.x * b.x; ay += a.y * b.y; az += a.z * b.z; aw += a.w * b.w;
            }
        }
        float s = (ax + ay) + (az + aw);
        #pragma unroll
        for (int off = 32; off; off >>= 1) s += __shfl_down(s, off, 64);
        if (lane == 0) u[row] = s;
    }
}

// partial[b][c] = dot(row_b[c*9808 : (c+1)*9808], u[same]) ; row 256 = center
__global__ __launch_bounds__(256) void k3_partial(const float* __restrict__ x,
                                                  const float* __restrict__ center,
                                                  const float* __restrict__ u,
                                                  float* __restrict__ part) {
    __shared__ float wred[4];
    const int bid = blockIdx.x;
    const int b = bid >> 3;
    const int c = bid & (CH - 1);
    const float* row = (b < BB) ? (x + (size_t)b * XCOLS) : center;
    const f2* r2 = reinterpret_cast<const f2*>(row);
    const f2* u2 = reinterpret_cast<const f2*>(u);
    const int j0 = c * CHLEN;
    float ax = 0.f, ay = 0.f;
    for (int j = j0 + threadIdx.x; j < j0 + CHLEN; j += 256) {
        f2 a = __builtin_nontemporal_load(&r2[j]);
        f2 uu = u2[j];
        ax += a.x * uu.x; ay += a.y * uu.y;
    }
    float s = ax + ay;
    #pragma unroll
    for (int off = 32; off; off >>= 1) s += __shfl_down(s, off, 64);
    const int wave = threadIdx.x >> 6;
    const int lane = threadIdx.x & 63;
    if (lane == 0) wred[wave] = s;
    __syncthreads();
    if (threadIdx.x == 0) part[bid] = (wred[0] + wred[1]) + (wred[2] + wred[3]);
}

// out[b] = rowsum_b - c.u + female*(v[1936]+w2[10]) + age*(v[1937]+w2[9]) + sum_k b1[k]*w2[k] + b2
__global__ __launch_bounds__(256) void k4_final(const float* __restrict__ x,
                                                const float* __restrict__ b1,
                                                const float* __restrict__ w2,
                                                const float* __restrict__ b2,
                                                const float* __restrict__ ws,
                                                float* __restrict__ out) {
    int b = threadIdx.x;
    if (b < BB) {
        float female = x[(size_t)b * XCOLS + IDIM];
        float age    = x[(size_t)b * XCOLS + IDIM + 1];
        float s = 0.f, cu = 0.f;
        #pragma unroll
        for (int c = 0; c < CH; ++c) {
            s  += ws[WS_P + b * CH + c];
            cu += ws[WS_P + BB * CH + c];
        }
        float cst = b2[0];
        #pragma unroll
        for (int k = 0; k < KK; ++k) cst += b1[k] * w2[k];
        out[b] = s - cu
               + female * (ws[WS_V + 1936] + w2[10])
               + age    * (ws[WS_V + 1937] + w2[9])
               + cst;
    }
}

extern "C" void kernel_launch(void* const* d_in, const int* in_sizes, int n_in,
                              void* d_out, int out_size, void* d_ws, size_t ws_size,
                              hipStream_t stream) {
    const float* x      = (const float*)d_in[0];
    const float* center = (const float*)d_in[1];
    const float* rot    = (const float*)d_in[2];
    const int*   feats  = (const int*)  d_in[3];
    const float* w1     = (const float*)d_in[4];
    const float* b1     = (const float*)d_in[5];
    const float* w2     = (const float*)d_in[6];
    const float* b2     = (const float*)d_in[7];
    float* ws  = (float*)d_ws;
    float* out = (float*)d_out;

    hipLaunchKernelGGL(k1_buildv,  dim3(1),        dim3(1024), 0, stream, feats, w1, w2, ws + WS_V);
    hipLaunchKernelGGL(k2_matvec,  dim3(2048),     dim3(256),  0, stream, rot, ws + WS_V, ws + WS_U);
    hipLaunchKernelGGL(k3_partial, dim3(257 * CH), dim3(256),  0, stream, x, center, ws + WS_U, ws + WS_P);
    hipLaunchKernelGGL(k4_final,   dim3(1),        dim3(256),  0, stream, x, b1, w2, b2, ws, out);
}